// Round 2
// baseline (1786.848 us; speedup 1.0000x reference)
//
#include <hip/hip_runtime.h>

// VQ nearest-codebook search + gather.
// x: [8,2048,1024] f32 -> N=16384 rows; embedding: [4096,1024] f32.
// out[n] = embedding[argmin_k ||x_n - e_k||^2]  (straight-through fwd == gather)
//
// Distance for argmin: s_k = ||e_k||^2 - 2 x.e_k   (||x||^2 is per-row constant).
// enorm in fp64 (k-varying -> affects argmin), dot in fp32 FMA.

#define NROWS 16384
#define DDIM  1024
#define KCB   4096

#define BN 128
#define BK 128
#define BD 16
#define KSPLIT 4
#define KPER (KCB / KSPLIT)   // 1024 codes per block

// ---------------- kernel 1: codebook squared norms (fp64 accum) ----------------
__global__ __launch_bounds__(256) void enorm_kernel(const float* __restrict__ e,
                                                    float* __restrict__ enorm) {
    const int k = blockIdx.x;
    const int tid = threadIdx.x;
    const float4 v = reinterpret_cast<const float4*>(e + (size_t)k * DDIM)[tid];
    double a = (double)v.x * v.x + (double)v.y * v.y + (double)v.z * v.z + (double)v.w * v.w;
    __shared__ double sm[256];
    sm[tid] = a;
    __syncthreads();
    for (int s = 128; s > 0; s >>= 1) {
        if (tid < s) sm[tid] += sm[tid + s];
        __syncthreads();
    }
    if (tid == 0) enorm[k] = (float)sm[0];
}

// ---------------- kernel 2: tiled distance + per-row argmin (K-split) ----------------
__global__ __launch_bounds__(256) void argmin_kernel(const float* __restrict__ x,
                                                     const float* __restrict__ e,
                                                     const float* __restrict__ enorm,
                                                     float* __restrict__ ps,
                                                     int* __restrict__ pi) {
    __shared__ float xs[BD][BN];    // 8 KB, transposed: xs[d][row]
    __shared__ float es[BD][BK];    // 8 KB, transposed: es[d][k]
    __shared__ float ens[BK];
    __shared__ float rs[BN][17];    // +1 pad
    __shared__ int   ri[BN][17];

    const int tid = threadIdx.x;
    const int tx = tid & 15;        // k-group  (8 codes each)
    const int ty = tid >> 4;        // row-group (8 rows each)
    const int n0 = blockIdx.x * BN;
    const int kbase = blockIdx.y * KPER;

    float best[8];
    int   bidx[8];
    #pragma unroll
    for (int m = 0; m < 8; ++m) { best[m] = 3.4e38f; bidx[m] = 0x7fffffff; }

    for (int kt = 0; kt < KPER; kt += BK) {
        const int k0 = kbase + kt;
        __syncthreads();                      // prior epilogue done with ens / tiles
        if (tid < BK) ens[tid] = enorm[k0 + tid];

        float acc[8][8];
        #pragma unroll
        for (int m = 0; m < 8; ++m)
            #pragma unroll
            for (int q = 0; q < 8; ++q) acc[m][q] = 0.f;

        for (int d0 = 0; d0 < DDIM; d0 += BD) {
            // stage x tile: BN rows x BD cols (2048 floats, 2x float4 per thread)
            #pragma unroll
            for (int r = 0; r < 2; ++r) {
                const int j = tid + r * 256;
                const int row = j >> 2;
                const int c = (j & 3) << 2;
                const float4 v = *reinterpret_cast<const float4*>(
                    x + (size_t)(n0 + row) * DDIM + d0 + c);
                xs[c + 0][row] = v.x;
                xs[c + 1][row] = v.y;
                xs[c + 2][row] = v.z;
                xs[c + 3][row] = v.w;
            }
            // stage e tile: BK rows x BD cols
            #pragma unroll
            for (int r = 0; r < 2; ++r) {
                const int j = tid + r * 256;
                const int row = j >> 2;
                const int c = (j & 3) << 2;
                const float4 v = *reinterpret_cast<const float4*>(
                    e + (size_t)(k0 + row) * DDIM + d0 + c);
                es[c + 0][row] = v.x;
                es[c + 1][row] = v.y;
                es[c + 2][row] = v.z;
                es[c + 3][row] = v.w;
            }
            __syncthreads();
            #pragma unroll
            for (int d = 0; d < BD; ++d) {
                const float4 xa = *reinterpret_cast<const float4*>(&xs[d][ty * 8]);
                const float4 xb = *reinterpret_cast<const float4*>(&xs[d][ty * 8 + 4]);
                const float4 ea = *reinterpret_cast<const float4*>(&es[d][tx * 8]);
                const float4 eb = *reinterpret_cast<const float4*>(&es[d][tx * 8 + 4]);
                const float xv[8] = {xa.x, xa.y, xa.z, xa.w, xb.x, xb.y, xb.z, xb.w};
                const float ev[8] = {ea.x, ea.y, ea.z, ea.w, eb.x, eb.y, eb.z, eb.w};
                #pragma unroll
                for (int m = 0; m < 8; ++m)
                    #pragma unroll
                    for (int q = 0; q < 8; ++q)
                        acc[m][q] = fmaf(xv[m], ev[q], acc[m][q]);
            }
            __syncthreads();
        }

        // epilogue: s = enorm - 2*dot; strict < keeps FIRST min (k ascending)
        #pragma unroll
        for (int m = 0; m < 8; ++m) {
            #pragma unroll
            for (int q = 0; q < 8; ++q) {
                const float s = fmaf(-2.f, acc[m][q], ens[tx * 8 + q]);
                const int ki = k0 + tx * 8 + q;
                if (s < best[m]) { best[m] = s; bidx[m] = ki; }
            }
        }
    }

    // cross-tx reduce: row = ty*8+m has 16 candidates (one per tx)
    #pragma unroll
    for (int m = 0; m < 8; ++m) {
        rs[ty * 8 + m][tx] = best[m];
        ri[ty * 8 + m][tx] = bidx[m];
    }
    __syncthreads();
    if (tid < BN) {
        float bs = rs[tid][0];
        int   bi = ri[tid][0];
        #pragma unroll
        for (int t = 1; t < 16; ++t) {
            const float s  = rs[tid][t];
            const int   i2 = ri[tid][t];
            if (s < bs || (s == bs && i2 < bi)) { bs = s; bi = i2; }
        }
        ps[(size_t)blockIdx.y * NROWS + n0 + tid] = bs;
        pi[(size_t)blockIdx.y * NROWS + n0 + tid] = bi;
    }
}

// ---------------- kernel 3: merge K-split partials + row gather ----------------
__global__ __launch_bounds__(256) void merge_gather_kernel(const float* __restrict__ e,
                                                           const float* __restrict__ ps,
                                                           const int* __restrict__ pi,
                                                           float* __restrict__ out) {
    const int n = blockIdx.x;
    float bs = ps[n];
    int   bi = pi[n];
    #pragma unroll
    for (int h = 1; h < KSPLIT; ++h) {
        const float s  = ps[(size_t)h * NROWS + n];
        const int   i2 = pi[(size_t)h * NROWS + n];
        if (s < bs || (s == bs && i2 < bi)) { bs = s; bi = i2; }
    }
    const float4* src = reinterpret_cast<const float4*>(e + (size_t)bi * DDIM);
    float4* dst = reinterpret_cast<float4*>(out + (size_t)n * DDIM);
    dst[threadIdx.x] = src[threadIdx.x];   // 256 * 16B = 4KB = one row
}

extern "C" void kernel_launch(void* const* d_in, const int* in_sizes, int n_in,
                              void* d_out, int out_size, void* d_ws, size_t ws_size,
                              hipStream_t stream) {
    const float* x = (const float*)d_in[0];
    const float* e = (const float*)d_in[1];
    float* out = (float*)d_out;

    char* ws = (char*)d_ws;
    float* enorm = (float*)ws;                                  // 16 KB
    float* ps    = (float*)(ws + 16 * 1024);                    // 256 KB
    int*   pi    = (int*)(ws + 16 * 1024 + KSPLIT * NROWS * 4); // 256 KB

    enorm_kernel<<<KCB, 256, 0, stream>>>(e, enorm);
    argmin_kernel<<<dim3(NROWS / BN, KSPLIT), 256, 0, stream>>>(x, e, enorm, ps, pi);
    merge_gather_kernel<<<NROWS, 256, 0, stream>>>(e, ps, pi, out);
}

// Round 3
// 568.790 us; speedup vs baseline: 3.1415x; 3.1415x over previous
//
#include <hip/hip_runtime.h>

// VQ nearest-codebook search + gather, fp16 split-3 MFMA version.
// x: [8,2048,1024] f32 -> N=16384 rows; embedding: [4096,1024] f32.
// out[n] = embedding[argmin_k ||x_n - e_k||^2]
//
// dist surrogate s_k = ||e_k||^2 - 2 x.e_k  (per-row ||x||^2 dropped).
// dot via fp16 split-3 MFMA: x.e ~= xh.eh + xl.eh + xh.el  (f32 accum).
// Error ~1e-4 << observed argmin gap slack (round-2 fp32 had zero flips).
//
// Fast path needs ~85MB workspace; falls back to proven fp32 kernel if
// ws_size is insufficient.

#define NROWS 16384
#define DDIM  1024
#define KCB   4096

typedef _Float16 f16x8 __attribute__((ext_vector_type(8)));
typedef _Float16 f16x4 __attribute__((ext_vector_type(4)));
typedef float    f32x4 __attribute__((ext_vector_type(4)));

// ---------------- codebook squared norms (fp64 accum) ----------------
__global__ __launch_bounds__(256) void enorm_kernel(const float* __restrict__ e,
                                                    float* __restrict__ enorm) {
    const int k = blockIdx.x;
    const int tid = threadIdx.x;
    const float4 v = reinterpret_cast<const float4*>(e + (size_t)k * DDIM)[tid];
    double a = (double)v.x * v.x + (double)v.y * v.y + (double)v.z * v.z + (double)v.w * v.w;
    __shared__ double sm[256];
    sm[tid] = a;
    __syncthreads();
    for (int s = 128; s > 0; s >>= 1) {
        if (tid < s) sm[tid] += sm[tid + s];
        __syncthreads();
    }
    if (tid == 0) enorm[k] = (float)sm[0];
}

// ---------------- f32 -> (hi, lo) fp16 split ----------------
__global__ __launch_bounds__(256) void split_kernel(const float4* __restrict__ in,
                                                    f16x4* __restrict__ hi,
                                                    f16x4* __restrict__ lo,
                                                    int n4) {
    const int i = blockIdx.x * 256 + threadIdx.x;
    if (i >= n4) return;
    const float4 v = in[i];
    const float vv[4] = {v.x, v.y, v.z, v.w};
    f16x4 h, l;
    #pragma unroll
    for (int j = 0; j < 4; ++j) {
        const _Float16 hh = (_Float16)vv[j];
        h[j] = hh;
        l[j] = (_Float16)(vv[j] - (float)hh);
    }
    hi[i] = h;
    lo[i] = l;
}

// ---------------- async global->LDS 16B helper ----------------
__device__ __forceinline__ void gld_lds16(const void* g, void* l) {
    __builtin_amdgcn_global_load_lds(
        (const __attribute__((address_space(1))) unsigned int*)g,
        (__attribute__((address_space(3))) unsigned int*)l,
        16, 0, 0);
}

// ---------------- MFMA split-3 distance + argmin ----------------
// grid: (KCB/128 cb fastest, NROWS/128 rb). block 256 = 4 waves (2x2 of 64x64).
// LDS tiles [128 rows][32 k] fp16, row stride 64B, 16B-chunk XOR swizzle:
//   phys_chunk = logical_chunk ^ ((row>>1)&3)
// applied on the per-lane GLOBAL source of global_load_lds (LDS dest linear)
// and on the ds_read side -> conflict-free (2-way) reads.
__global__ __launch_bounds__(256, 2) void mfma_argmin_kernel(
    const _Float16* __restrict__ xh, const _Float16* __restrict__ xl,
    const _Float16* __restrict__ eh, const _Float16* __restrict__ el,
    const float* __restrict__ enorm,
    float* __restrict__ ps, int* __restrict__ pi) {

    __shared__ __align__(16) _Float16 s_xh[128 * 32];
    __shared__ __align__(16) _Float16 s_xl[128 * 32];
    __shared__ __align__(16) _Float16 s_eh[128 * 32];
    __shared__ __align__(16) _Float16 s_el[128 * 32];
    __shared__ float s_ens[128];
    __shared__ float s_rs[128][2];
    __shared__ int   s_ri[128][2];

    const int tid = threadIdx.x;
    const int l   = tid & 63;
    const int w   = tid >> 6;        // wave 0..3
    const int wr  = w >> 1;          // wave row 0..1
    const int wc  = w & 1;           // wave col 0..1
    const int n0  = blockIdx.y * 128;
    const int k0  = blockIdx.x * 128;

    if (tid < 128) s_ens[tid] = enorm[k0 + tid];

    // ---- stager precompute (per lane): row within 64-row half, swizzled col
    const int srow = w * 16 + (l >> 2);                         // 0..63
    const int scol = (((l & 3) ^ ((l >> 3) & 3)) << 3);         // fp16 elems
    // ---- reader precompute: byte offset incl. swizzle
    const int sw   = (((l >> 4) ^ ((l >> 1) & 3)) << 4);        // byte chunk
    const int aoff = (wr * 64 + (l & 15)) * 64 + sw;            // A frag m=0
    const int boff = (wc * 64 + (l & 15)) * 64 + sw;            // B frag n=0

    f32x4 acc[4][4];
    #pragma unroll
    for (int m = 0; m < 4; ++m)
        #pragma unroll
        for (int n = 0; n < 4; ++n)
            acc[m][n] = (f32x4)0.f;

    const char* cxh = (const char*)s_xh;
    const char* cxl = (const char*)s_xl;
    const char* ceh = (const char*)s_eh;
    const char* cel = (const char*)s_el;

    for (int d0 = 0; d0 < DDIM; d0 += 32) {
        // ---- stage 4 arrays, 2 instructions each (1KB per instr per wave)
        #pragma unroll
        for (int i = 0; i < 2; ++i) {
            const size_t ro = (size_t)(n0 + i * 64 + srow) * DDIM + d0 + scol;
            const size_t ko = (size_t)(k0 + i * 64 + srow) * DDIM + d0 + scol;
            const int lb = w * 512 + i * 2048;   // fp16 elems = w*1KB + i*4KB
            gld_lds16(xh + ro, (void*)(s_xh + lb));
            gld_lds16(xl + ro, (void*)(s_xl + lb));
            gld_lds16(eh + ko, (void*)(s_eh + lb));
            gld_lds16(el + ko, (void*)(s_el + lb));
        }
        __syncthreads();   // drains vmcnt, tiles ready

        f16x8 bh[4], bl[4];
        #pragma unroll
        for (int n = 0; n < 4; ++n) {
            bh[n] = *(const f16x8*)(ceh + boff + n * 1024);
            bl[n] = *(const f16x8*)(cel + boff + n * 1024);
        }
        #pragma unroll
        for (int m = 0; m < 4; ++m) {
            const f16x8 amh = *(const f16x8*)(cxh + aoff + m * 1024);
            const f16x8 aml = *(const f16x8*)(cxl + aoff + m * 1024);
            #pragma unroll
            for (int n = 0; n < 4; ++n) {
                acc[m][n] = __builtin_amdgcn_mfma_f32_16x16x32_f16(amh, bh[n], acc[m][n], 0, 0, 0);
                acc[m][n] = __builtin_amdgcn_mfma_f32_16x16x32_f16(aml, bh[n], acc[m][n], 0, 0, 0);
                acc[m][n] = __builtin_amdgcn_mfma_f32_16x16x32_f16(amh, bl[n], acc[m][n], 0, 0, 0);
            }
        }
        __syncthreads();   // protect LDS before next overwrite
    }

    // ---- epilogue: s = enorm - 2*dot, (s,idx)-lexicographic argmin
    // C layout (16x16x32): col = l&15, row = (l>>4)*4 + reg  [verified m89/m91]
    #pragma unroll
    for (int m = 0; m < 4; ++m) {
        #pragma unroll
        for (int reg = 0; reg < 4; ++reg) {
            float bs = 3.4e38f;
            int   bi = 0x7fffffff;
            #pragma unroll
            for (int n = 0; n < 4; ++n) {
                const int cl = wc * 64 + n * 16 + (l & 15);
                const float s = fmaf(-2.f, acc[m][n][reg], s_ens[cl]);
                const int ki = k0 + cl;
                if (s < bs || (s == bs && ki < bi)) { bs = s; bi = ki; }
            }
            #pragma unroll
            for (int d = 1; d < 16; d <<= 1) {
                const float os = __shfl_xor(bs, d);
                const int   oi = __shfl_xor(bi, d);
                if (os < bs || (os == bs && oi < bi)) { bs = os; bi = oi; }
            }
            if ((l & 15) == 0) {
                const int R = wr * 64 + m * 16 + (l >> 4) * 4 + reg;
                s_rs[R][wc] = bs;
                s_ri[R][wc] = bi;
            }
        }
    }
    __syncthreads();
    if (tid < 128) {
        float b0 = s_rs[tid][0]; int i0 = s_ri[tid][0];
        const float b1 = s_rs[tid][1]; const int i1 = s_ri[tid][1];
        if (b1 < b0 || (b1 == b0 && i1 < i0)) { b0 = b1; i0 = i1; }
        ps[(size_t)blockIdx.x * NROWS + n0 + tid] = b0;
        pi[(size_t)blockIdx.x * NROWS + n0 + tid] = i0;
    }
}

// ---------------- merge 32 col-split partials + row gather ----------------
__global__ __launch_bounds__(256) void merge_gather32_kernel(const float* __restrict__ e,
                                                             const float* __restrict__ ps,
                                                             const int* __restrict__ pi,
                                                             float* __restrict__ out) {
    const int n = blockIdx.x;
    const int tid = threadIdx.x;
    __shared__ int sbi;
    if (tid < 32) {
        float bs = ps[(size_t)tid * NROWS + n];
        int   bi = pi[(size_t)tid * NROWS + n];
        #pragma unroll
        for (int d = 1; d < 32; d <<= 1) {
            const float os = __shfl_xor(bs, d);
            const int   oi = __shfl_xor(bi, d);
            if (os < bs || (os == bs && oi < bi)) { bs = os; bi = oi; }
        }
        if (tid == 0) sbi = bi;
    }
    __syncthreads();
    const float4* src = reinterpret_cast<const float4*>(e + (size_t)sbi * DDIM);
    reinterpret_cast<float4*>(out + (size_t)n * DDIM)[tid] = src[tid];
}

// =================== fp32 fallback path (proven, round 2) ===================
#define BN 128
#define BK 128
#define BD 16
#define KSPLIT 4
#define KPER (KCB / KSPLIT)

__global__ __launch_bounds__(256) void argmin_kernel(const float* __restrict__ x,
                                                     const float* __restrict__ e,
                                                     const float* __restrict__ enorm,
                                                     float* __restrict__ ps,
                                                     int* __restrict__ pi) {
    __shared__ float xs[BD][BN];
    __shared__ float es[BD][BK];
    __shared__ float ens[BK];
    __shared__ float rs[BN][17];
    __shared__ int   ri[BN][17];

    const int tid = threadIdx.x;
    const int tx = tid & 15;
    const int ty = tid >> 4;
    const int n0 = blockIdx.x * BN;
    const int kbase = blockIdx.y * KPER;

    float best[8];
    int   bidx[8];
    #pragma unroll
    for (int m = 0; m < 8; ++m) { best[m] = 3.4e38f; bidx[m] = 0x7fffffff; }

    for (int kt = 0; kt < KPER; kt += BK) {
        const int k0 = kbase + kt;
        __syncthreads();
        if (tid < BK) ens[tid] = enorm[k0 + tid];

        float acc[8][8];
        #pragma unroll
        for (int m = 0; m < 8; ++m)
            #pragma unroll
            for (int q = 0; q < 8; ++q) acc[m][q] = 0.f;

        for (int d0 = 0; d0 < DDIM; d0 += BD) {
            #pragma unroll
            for (int r = 0; r < 2; ++r) {
                const int j = tid + r * 256;
                const int row = j >> 2;
                const int c = (j & 3) << 2;
                const float4 v = *reinterpret_cast<const float4*>(
                    x + (size_t)(n0 + row) * DDIM + d0 + c);
                xs[c + 0][row] = v.x; xs[c + 1][row] = v.y;
                xs[c + 2][row] = v.z; xs[c + 3][row] = v.w;
            }
            #pragma unroll
            for (int r = 0; r < 2; ++r) {
                const int j = tid + r * 256;
                const int row = j >> 2;
                const int c = (j & 3) << 2;
                const float4 v = *reinterpret_cast<const float4*>(
                    e + (size_t)(k0 + row) * DDIM + d0 + c);
                es[c + 0][row] = v.x; es[c + 1][row] = v.y;
                es[c + 2][row] = v.z; es[c + 3][row] = v.w;
            }
            __syncthreads();
            #pragma unroll
            for (int d = 0; d < BD; ++d) {
                const float4 xa = *reinterpret_cast<const float4*>(&xs[d][ty * 8]);
                const float4 xb = *reinterpret_cast<const float4*>(&xs[d][ty * 8 + 4]);
                const float4 ea = *reinterpret_cast<const float4*>(&es[d][tx * 8]);
                const float4 eb = *reinterpret_cast<const float4*>(&es[d][tx * 8 + 4]);
                const float xv[8] = {xa.x, xa.y, xa.z, xa.w, xb.x, xb.y, xb.z, xb.w};
                const float ev[8] = {ea.x, ea.y, ea.z, ea.w, eb.x, eb.y, eb.z, eb.w};
                #pragma unroll
                for (int m = 0; m < 8; ++m)
                    #pragma unroll
                    for (int q = 0; q < 8; ++q)
                        acc[m][q] = fmaf(xv[m], ev[q], acc[m][q]);
            }
            __syncthreads();
        }

        #pragma unroll
        for (int m = 0; m < 8; ++m) {
            #pragma unroll
            for (int q = 0; q < 8; ++q) {
                const float s = fmaf(-2.f, acc[m][q], ens[tx * 8 + q]);
                const int ki = k0 + tx * 8 + q;
                if (s < best[m]) { best[m] = s; bidx[m] = ki; }
            }
        }
    }

    #pragma unroll
    for (int m = 0; m < 8; ++m) {
        rs[ty * 8 + m][tx] = best[m];
        ri[ty * 8 + m][tx] = bidx[m];
    }
    __syncthreads();
    if (tid < BN) {
        float bs = rs[tid][0];
        int   bi = ri[tid][0];
        #pragma unroll
        for (int t = 1; t < 16; ++t) {
            const float s  = rs[tid][t];
            const int   i2 = ri[tid][t];
            if (s < bs || (s == bs && i2 < bi)) { bs = s; bi = i2; }
        }
        ps[(size_t)blockIdx.y * NROWS + n0 + tid] = bs;
        pi[(size_t)blockIdx.y * NROWS + n0 + tid] = bi;
    }
}

__global__ __launch_bounds__(256) void merge_gather_kernel(const float* __restrict__ e,
                                                           const float* __restrict__ ps,
                                                           const int* __restrict__ pi,
                                                           float* __restrict__ out) {
    const int n = blockIdx.x;
    float bs = ps[n];
    int   bi = pi[n];
    #pragma unroll
    for (int h = 1; h < KSPLIT; ++h) {
        const float s  = ps[(size_t)h * NROWS + n];
        const int   i2 = pi[(size_t)h * NROWS + n];
        if (s < bs || (s == bs && i2 < bi)) { bs = s; bi = i2; }
    }
    const float4* src = reinterpret_cast<const float4*>(e + (size_t)bi * DDIM);
    float4* dst = reinterpret_cast<float4*>(out + (size_t)n * DDIM);
    dst[threadIdx.x] = src[threadIdx.x];
}

// =================== launcher ===================
extern "C" void kernel_launch(void* const* d_in, const int* in_sizes, int n_in,
                              void* d_out, int out_size, void* d_ws, size_t ws_size,
                              hipStream_t stream) {
    const float* x = (const float*)d_in[0];
    const float* e = (const float*)d_in[1];
    float* out = (float*)d_out;
    char* ws = (char*)d_ws;

    const size_t MB = 1024 * 1024;
    const size_t need = 85 * MB;

    if (ws_size >= need) {
        // fast path: fp16 split-3 MFMA
        float* enorm = (float*)(ws);                       // 16 KB @ 0
        float* ps    = (float*)(ws + 1 * MB);              // 2 MB
        int*   pi    = (int*)  (ws + 3 * MB);              // 2 MB
        _Float16* xh = (_Float16*)(ws + 5 * MB);           // 32 MB
        _Float16* xl = (_Float16*)(ws + 37 * MB);          // 32 MB
        _Float16* ehp = (_Float16*)(ws + 69 * MB);         // 8 MB
        _Float16* elp = (_Float16*)(ws + 77 * MB);         // 8 MB

        enorm_kernel<<<KCB, 256, 0, stream>>>(e, enorm);
        split_kernel<<<(NROWS * DDIM / 4 + 255) / 256, 256, 0, stream>>>(
            (const float4*)x, (f16x4*)xh, (f16x4*)xl, NROWS * DDIM / 4);
        split_kernel<<<(KCB * DDIM / 4 + 255) / 256, 256, 0, stream>>>(
            (const float4*)e, (f16x4*)ehp, (f16x4*)elp, KCB * DDIM / 4);
        mfma_argmin_kernel<<<dim3(KCB / 128, NROWS / 128), 256, 0, stream>>>(
            xh, xl, ehp, elp, enorm, ps, pi);
        merge_gather32_kernel<<<NROWS, 256, 0, stream>>>(e, ps, pi, out);
    } else {
        // fallback: proven fp32 path
        float* enorm = (float*)ws;
        float* ps    = (float*)(ws + 16 * 1024);
        int*   pi    = (int*)(ws + 16 * 1024 + KSPLIT * NROWS * 4);

        enorm_kernel<<<KCB, 256, 0, stream>>>(e, enorm);
        argmin_kernel<<<dim3(NROWS / BN, KSPLIT), 256, 0, stream>>>(x, e, enorm, ps, pi);
        merge_gather_kernel<<<NROWS, 256, 0, stream>>>(e, ps, pi, out);
    }
}

// Round 5
// 511.513 us; speedup vs baseline: 3.4933x; 1.1120x over previous
//
#include <hip/hip_runtime.h>

// VQ nearest-codebook search + gather, single-pass fp16 MFMA + exact refine.
// x: [8,2048,1024] f32 -> N=16384 rows; embedding: [4096,1024] f32.
// out[n] = embedding[argmin_k ||x_n - e_k||^2]
//
// Approx distance s~_k = ||e_k||^2 - 2 * dot_fp16(x,e_k) via one MFMA pass
// (error std ~0.026, max ~0.15 over 67M values; typical best/2nd gap ~22).
// Per row, each of the 32 k-blocks keeps its top-2 (s,idx). Refine kernel:
// global approx min over the 64 saved; if >1 candidate within MARGIN=1.0,
// recompute those exactly in fp64 and argmin (first-index tie semantics).

#define NROWS 16384
#define DDIM  1024
#define KCB   4096
#define MARGIN 1.0f

typedef _Float16 f16x8 __attribute__((ext_vector_type(8)));
typedef float    f32x4 __attribute__((ext_vector_type(4)));

// ---------------- codebook squared norms (fp64 accum) ----------------
__global__ __launch_bounds__(256) void enorm_kernel(const float* __restrict__ e,
                                                    float* __restrict__ enorm) {
    const int k = blockIdx.x;
    const int tid = threadIdx.x;
    const float4 v = reinterpret_cast<const float4*>(e + (size_t)k * DDIM)[tid];
    double a = (double)v.x * v.x + (double)v.y * v.y + (double)v.z * v.z + (double)v.w * v.w;
    __shared__ double sm[256];
    sm[tid] = a;
    __syncthreads();
    for (int s = 128; s > 0; s >>= 1) {
        if (tid < s) sm[tid] += sm[tid + s];
        __syncthreads();
    }
    if (tid == 0) enorm[k] = (float)sm[0];
}

// ---------------- f32 -> fp16 convert (8 elems/thread) ----------------
__global__ __launch_bounds__(256) void cvt16_kernel(const float* __restrict__ in,
                                                    _Float16* __restrict__ out, int n8) {
    const int i = blockIdx.x * 256 + threadIdx.x;
    if (i >= n8) return;
    const float4 a = reinterpret_cast<const float4*>(in)[2 * i];
    const float4 b = reinterpret_cast<const float4*>(in)[2 * i + 1];
    f16x8 h;
    h[0] = (_Float16)a.x; h[1] = (_Float16)a.y; h[2] = (_Float16)a.z; h[3] = (_Float16)a.w;
    h[4] = (_Float16)b.x; h[5] = (_Float16)b.y; h[6] = (_Float16)b.z; h[7] = (_Float16)b.w;
    reinterpret_cast<f16x8*>(out)[i] = h;
}

// ---------------- async global->LDS 16B helper ----------------
__device__ __forceinline__ void gld_lds16(const void* g, void* l) {
    __builtin_amdgcn_global_load_lds(
        (const __attribute__((address_space(1))) unsigned int*)g,
        (__attribute__((address_space(3))) unsigned int*)l,
        16, 0, 0);
}

// sorted-pair merge: (b1,i1,b2,i2) <- top2 of union with (c1,j1,c2,j2); both sorted
__device__ __forceinline__ void top2_merge(float& b1, int& i1, float& b2, int& i2,
                                           float c1, int j1, float c2, int j2) {
    if (c1 < b1 || (c1 == b1 && j1 < i1)) {
        float nb2; int ni2;
        if (b1 < c2 || (b1 == c2 && i1 < j2)) { nb2 = b1; ni2 = i1; }
        else { nb2 = c2; ni2 = j2; }
        b2 = nb2; i2 = ni2; b1 = c1; i1 = j1;
    } else if (c1 < b2 || (c1 == b2 && j1 < i2)) {
        b2 = c1; i2 = j1;
    }
}

// ---------------- MFMA single-pass distance + per-block top-2 ----------------
// grid (KCB/128 cb fastest, NROWS/128 rb), 256 thr = 4 waves (2x2 of 64x64).
// LDS tiles [128 rows][64 k] fp16, 128B row stride, 16B-chunk swizzle:
//   phys_chunk = logical_chunk ^ (row & 7)
// applied on per-lane GLOBAL source of global_load_lds (LDS dest linear) and
// on the ds_read byte offset -> 8 consecutive lanes hit 8 distinct 16B slots.
__global__ __launch_bounds__(256, 2) void mfma_top2_kernel(
    const _Float16* __restrict__ xh, const _Float16* __restrict__ eh,
    const float* __restrict__ enorm,
    float* __restrict__ ps, int* __restrict__ pi) {

    __shared__ __align__(16) _Float16 s_x[128 * 64];   // 16 KB
    __shared__ __align__(16) _Float16 s_e[128 * 64];   // 16 KB
    __shared__ float s_ens[128];
    __shared__ float s_rs[128][2][2];
    __shared__ int   s_ri[128][2][2];

    const int tid = threadIdx.x;
    const int l   = tid & 63;
    const int w   = tid >> 6;        // wave 0..3
    const int wr  = w >> 1;
    const int wc  = w & 1;
    const int n0  = blockIdx.y * 128;
    const int k0  = blockIdx.x * 128;

    if (tid < 128) s_ens[tid] = enorm[k0 + tid];

    // stager: per instr, 8 rows x 128B. lane -> row (l>>3), phys chunk (l&7);
    // global col chunk = phys ^ (row&7) = (l&7) ^ (l>>3)
    const int srow = l >> 3;
    const int scol = ((l & 7) ^ (l >> 3)) * 8;          // fp16 elems
    // reader: A row, B row, k-group
    const int arow = wr * 64 + (l & 15);
    const int brow = wc * 64 + (l & 15);
    const int g    = l >> 4;                            // 0..3

    f32x4 acc[4][4];
    #pragma unroll
    for (int m = 0; m < 4; ++m)
        #pragma unroll
        for (int n = 0; n < 4; ++n)
            acc[m][n] = (f32x4)0.f;

    const char* cx = (const char*)s_x;
    const char* ce = (const char*)s_e;

    for (int d0 = 0; d0 < DDIM; d0 += 64) {
        #pragma unroll
        for (int i = 0; i < 4; ++i) {
            const int rb = (w * 4 + i) * 8;             // row base
            gld_lds16(xh + (size_t)(n0 + rb + srow) * DDIM + d0 + scol,
                      (void*)(s_x + (w * 4 + i) * 512));
            gld_lds16(eh + (size_t)(k0 + rb + srow) * DDIM + d0 + scol,
                      (void*)(s_e + (w * 4 + i) * 512));
        }
        __syncthreads();   // drains vmcnt; tiles ready

        #pragma unroll
        for (int ks = 0; ks < 2; ++ks) {
            const int ph = (((ks * 4 + g) ^ (l & 7)) << 4);   // swizzled byte chunk
            f16x8 a[4], b[4];
            #pragma unroll
            for (int m = 0; m < 4; ++m)
                a[m] = *(const f16x8*)(cx + (arow + m * 16) * 128 + ph);
            #pragma unroll
            for (int n = 0; n < 4; ++n)
                b[n] = *(const f16x8*)(ce + (brow + n * 16) * 128 + ph);
            #pragma unroll
            for (int m = 0; m < 4; ++m)
                #pragma unroll
                for (int n = 0; n < 4; ++n)
                    acc[m][n] = __builtin_amdgcn_mfma_f32_16x16x32_f16(a[m], b[n], acc[m][n], 0, 0, 0);
        }
        __syncthreads();   // protect LDS before next overwrite
    }

    // epilogue: s = enorm - 2*dot; per-row top-2 across this block's 128 cols.
    // C layout (16x16x32): col = l&15, row = (l>>4)*4 + reg  [proven round 3]
    #pragma unroll
    for (int m = 0; m < 4; ++m) {
        #pragma unroll
        for (int reg = 0; reg < 4; ++reg) {
            float b1 = 3.4e38f, b2 = 3.4e38f;
            int   i1 = 0x7fffffff, i2 = 0x7fffffff;
            #pragma unroll
            for (int n = 0; n < 4; ++n) {
                const int cl = wc * 64 + n * 16 + (l & 15);
                const float s = fmaf(-2.f, acc[m][n][reg], s_ens[cl]);
                const int ki = k0 + cl;
                if (s < b1 || (s == b1 && ki < i1)) { b2 = b1; i2 = i1; b1 = s; i1 = ki; }
                else if (s < b2 || (s == b2 && ki < i2)) { b2 = s; i2 = ki; }
            }
            #pragma unroll
            for (int d = 1; d < 16; d <<= 1) {
                const float c1 = __shfl_xor(b1, d); const int j1 = __shfl_xor(i1, d);
                const float c2 = __shfl_xor(b2, d); const int j2 = __shfl_xor(i2, d);
                top2_merge(b1, i1, b2, i2, c1, j1, c2, j2);
            }
            if ((l & 15) == 0) {
                const int R = wr * 64 + m * 16 + (l >> 4) * 4 + reg;
                s_rs[R][wc][0] = b1; s_ri[R][wc][0] = i1;
                s_rs[R][wc][1] = b2; s_ri[R][wc][1] = i2;
            }
        }
    }
    __syncthreads();
    if (tid < 128) {
        float b1 = s_rs[tid][0][0], b2 = s_rs[tid][0][1];
        int   i1 = s_ri[tid][0][0], i2 = s_ri[tid][0][1];
        top2_merge(b1, i1, b2, i2,
                   s_rs[tid][1][0], s_ri[tid][1][0],
                   s_rs[tid][1][1], s_ri[tid][1][1]);
        const size_t o0 = (size_t)(blockIdx.x * 2 + 0) * NROWS + n0 + tid;
        const size_t o1 = (size_t)(blockIdx.x * 2 + 1) * NROWS + n0 + tid;
        ps[o0] = b1; pi[o0] = i1;
        ps[o1] = b2; pi[o1] = i2;
    }
}

// ---------------- candidate merge + fp64 exact refine + gather ----------------
__global__ __launch_bounds__(256) void refine_gather_kernel(
    const float* __restrict__ x, const float* __restrict__ e,
    const float* __restrict__ ps, const int* __restrict__ pi,
    float* __restrict__ out) {
    const int n = blockIdx.x;
    const int tid = threadIdx.x;
    __shared__ int s_cand[8];
    __shared__ int s_ncand;
    __shared__ double s_red[256];

    if (tid < 64) {
        const float s = ps[(size_t)tid * NROWS + n];
        const int  ki = pi[(size_t)tid * NROWS + n];
        float mn = s;
        #pragma unroll
        for (int d = 1; d < 64; d <<= 1) mn = fminf(mn, __shfl_xor(mn, d));
        const bool cand = (s <= mn + MARGIN);
        const unsigned long long bal = __ballot(cand);
        if (tid == 0) s_ncand = (int)__popcll(bal);
        if (cand) {
            const int r = (int)__popcll(bal & ((1ull << tid) - 1ull));
            if (r < 8) s_cand[r] = ki;
        }
    }
    __syncthreads();
    int nc = s_ncand;
    int bi;
    if (nc == 1) {
        bi = s_cand[0];
    } else {
        if (nc > 8) nc = 8;
        const float4 xv = *reinterpret_cast<const float4*>(x + (size_t)n * DDIM + tid * 4);
        double bs = 1e300;
        int bidx = 0x7fffffff;
        for (int c = 0; c < nc; ++c) {
            const int ki = s_cand[c];
            const float4 ev = *reinterpret_cast<const float4*>(e + (size_t)ki * DDIM + tid * 4);
            double p = 0.0;
            p += (double)ev.x * ev.x - 2.0 * (double)xv.x * ev.x;
            p += (double)ev.y * ev.y - 2.0 * (double)xv.y * ev.y;
            p += (double)ev.z * ev.z - 2.0 * (double)xv.z * ev.z;
            p += (double)ev.w * ev.w - 2.0 * (double)xv.w * ev.w;
            s_red[tid] = p;
            __syncthreads();
            for (int st = 128; st > 0; st >>= 1) {
                if (tid < st) s_red[tid] += s_red[tid + st];
                __syncthreads();
            }
            const double sc = s_red[0];
            __syncthreads();   // before next overwrite
            if (sc < bs || (sc == bs && ki < bidx)) { bs = sc; bidx = ki; }
        }
        bi = bidx;  // deterministic, identical on all threads
    }
    const float4* src = reinterpret_cast<const float4*>(e + (size_t)bi * DDIM);
    reinterpret_cast<float4*>(out + (size_t)n * DDIM)[tid] = src[tid];
}

// =================== fp32 fallback path (proven round 2; tiny ws) ===================
#define BN 128
#define BK 128
#define BD 16
#define KSPLIT 4
#define KPER (KCB / KSPLIT)

__global__ __launch_bounds__(256) void argmin_kernel(const float* __restrict__ x,
                                                     const float* __restrict__ e,
                                                     const float* __restrict__ enorm,
                                                     float* __restrict__ ps,
                                                     int* __restrict__ pi) {
    __shared__ float xs[BD][BN];
    __shared__ float es[BD][BK];
    __shared__ float ens[BK];
    __shared__ float rs[BN][17];
    __shared__ int   ri[BN][17];

    const int tid = threadIdx.x;
    const int tx = tid & 15;
    const int ty = tid >> 4;
    const int n0 = blockIdx.x * BN;
    const int kbase = blockIdx.y * KPER;

    float best[8];
    int   bidx[8];
    #pragma unroll
    for (int m = 0; m < 8; ++m) { best[m] = 3.4e38f; bidx[m] = 0x7fffffff; }

    for (int kt = 0; kt < KPER; kt += BK) {
        const int k0 = kbase + kt;
        __syncthreads();
        if (tid < BK) ens[tid] = enorm[k0 + tid];

        float acc[8][8];
        #pragma unroll
        for (int m = 0; m < 8; ++m)
            #pragma unroll
            for (int q = 0; q < 8; ++q) acc[m][q] = 0.f;

        for (int d0 = 0; d0 < DDIM; d0 += BD) {
            #pragma unroll
            for (int r = 0; r < 2; ++r) {
                const int j = tid + r * 256;
                const int row = j >> 2;
                const int c = (j & 3) << 2;
                const float4 v = *reinterpret_cast<const float4*>(
                    x + (size_t)(n0 + row) * DDIM + d0 + c);
                xs[c + 0][row] = v.x; xs[c + 1][row] = v.y;
                xs[c + 2][row] = v.z; xs[c + 3][row] = v.w;
            }
            #pragma unroll
            for (int r = 0; r < 2; ++r) {
                const int j = tid + r * 256;
                const int row = j >> 2;
                const int c = (j & 3) << 2;
                const float4 v = *reinterpret_cast<const float4*>(
                    e + (size_t)(k0 + row) * DDIM + d0 + c);
                es[c + 0][row] = v.x; es[c + 1][row] = v.y;
                es[c + 2][row] = v.z; es[c + 3][row] = v.w;
            }
            __syncthreads();
            #pragma unroll
            for (int d = 0; d < BD; ++d) {
                const float4 xa = *reinterpret_cast<const float4*>(&xs[d][ty * 8]);
                const float4 xb = *reinterpret_cast<const float4*>(&xs[d][ty * 8 + 4]);
                const float4 ea = *reinterpret_cast<const float4*>(&es[d][tx * 8]);
                const float4 eb = *reinterpret_cast<const float4*>(&es[d][tx * 8 + 4]);
                const float xv[8] = {xa.x, xa.y, xa.z, xa.w, xb.x, xb.y, xb.z, xb.w};
                const float ev[8] = {ea.x, ea.y, ea.z, ea.w, eb.x, eb.y, eb.z, eb.w};
                #pragma unroll
                for (int m = 0; m < 8; ++m)
                    #pragma unroll
                    for (int q = 0; q < 8; ++q)
                        acc[m][q] = fmaf(xv[m], ev[q], acc[m][q]);
            }
            __syncthreads();
        }

        #pragma unroll
        for (int m = 0; m < 8; ++m) {
            #pragma unroll
            for (int q = 0; q < 8; ++q) {
                const float s = fmaf(-2.f, acc[m][q], ens[tx * 8 + q]);
                const int ki = k0 + tx * 8 + q;
                if (s < best[m]) { best[m] = s; bidx[m] = ki; }
            }
        }
    }

    #pragma unroll
    for (int m = 0; m < 8; ++m) {
        rs[ty * 8 + m][tx] = best[m];
        ri[ty * 8 + m][tx] = bidx[m];
    }
    __syncthreads();
    if (tid < BN) {
        float bs = rs[tid][0];
        int   bi = ri[tid][0];
        #pragma unroll
        for (int t = 1; t < 16; ++t) {
            const float s  = rs[tid][t];
            const int   i2 = ri[tid][t];
            if (s < bs || (s == bs && i2 < bi)) { bs = s; bi = i2; }
        }
        ps[(size_t)blockIdx.y * NROWS + n0 + tid] = bs;
        pi[(size_t)blockIdx.y * NROWS + n0 + tid] = bi;
    }
}

__global__ __launch_bounds__(256) void merge_gather_kernel(const float* __restrict__ e,
                                                           const float* __restrict__ ps,
                                                           const int* __restrict__ pi,
                                                           float* __restrict__ out) {
    const int n = blockIdx.x;
    float bs = ps[n];
    int   bi = pi[n];
    #pragma unroll
    for (int h = 1; h < KSPLIT; ++h) {
        const float s  = ps[(size_t)h * NROWS + n];
        const int   i2 = pi[(size_t)h * NROWS + n];
        if (s < bs || (s == bs && i2 < bi)) { bs = s; bi = i2; }
    }
    const float4* src = reinterpret_cast<const float4*>(e + (size_t)bi * DDIM);
    float4* dst = reinterpret_cast<float4*>(out + (size_t)n * DDIM);
    dst[threadIdx.x] = src[threadIdx.x];
}

// =================== launcher ===================
extern "C" void kernel_launch(void* const* d_in, const int* in_sizes, int n_in,
                              void* d_out, int out_size, void* d_ws, size_t ws_size,
                              hipStream_t stream) {
    const float* x = (const float*)d_in[0];
    const float* e = (const float*)d_in[1];
    float* out = (float*)d_out;
    char* ws = (char*)d_ws;

    const size_t MB = 1024 * 1024;
    const size_t need = 56 * MB;

    if (ws_size >= need) {
        float*    enorm = (float*)(ws);              // 16 KB
        float*    ps    = (float*)(ws + 1 * MB);     // 4 MB (64 entries x NROWS)
        int*      pi    = (int*)  (ws + 6 * MB);     // 4 MB
        _Float16* xh    = (_Float16*)(ws + 16 * MB); // 32 MB
        _Float16* ehp   = (_Float16*)(ws + 48 * MB); // 8 MB

        enorm_kernel<<<KCB, 256, 0, stream>>>(e, enorm);
        cvt16_kernel<<<(NROWS * DDIM / 8 + 255) / 256, 256, 0, stream>>>(x, xh, NROWS * DDIM / 8);
        cvt16_kernel<<<(KCB * DDIM / 8 + 255) / 256, 256, 0, stream>>>(e, ehp, KCB * DDIM / 8);
        mfma_top2_kernel<<<dim3(KCB / 128, NROWS / 128), 256, 0, stream>>>(
            xh, ehp, enorm, ps, pi);
        refine_gather_kernel<<<NROWS, 256, 0, stream>>>(x, e, ps, pi, out);
    } else {
        float* enorm = (float*)ws;
        float* ps    = (float*)(ws + 16 * 1024);
        int*   pi    = (int*)(ws + 16 * 1024 + KSPLIT * NROWS * 4);

        enorm_kernel<<<KCB, 256, 0, stream>>>(e, enorm);
        argmin_kernel<<<dim3(NROWS / BN, KSPLIT), 256, 0, stream>>>(x, e, enorm, ps, pi);
        merge_gather_kernel<<<NROWS, 256, 0, stream>>>(e, ps, pi, out);
    }
}